// Round 8
// baseline (87.032 us; speedup 1.0000x reference)
//
#include <hip/hip_runtime.h>

#define NB 8
#define NPTS 4096
#define IPT 16                      // a-points per thread (scalar A-side)
#define OUT_SCALE (1.0f / (float)(NPTS * NB))

typedef float v2f __attribute__((ext_vector_type(2)));

#if defined(__has_builtin) && __has_builtin(__builtin_elementwise_fma)
#define V2FMA(a, b, c) __builtin_elementwise_fma((a), (b), (c))
#else
static __device__ inline v2f V2FMA(v2f a, v2f b, v2f c) {
    v2f r; r.x = fmaf(a.x, b.x, c.x); r.y = fmaf(a.y, b.y, c.y); return r;
}
#endif

static __device__ inline v2f splat2(float s) { v2f r; r.x = s; r.y = s; return r; }

// ---------------- main: grid (NPTS/(256*IPT)=1, NB, 2*CH), block 256 ----------------
// LDS packed over m-PAIRS: per pair mp, 4 v2f = {cx[2mp],cx[2mp+1]},{cy..},{cz..},{cw..} (32B)
// -> exactly 2 ds_read_b128 per 2-m per wave. A-side scalar (splats hoisted).
// Inner: per 2 m-pairs per point: 6 v_pk_fma + 2 v_min3 (min(vmin, t0, t1) per pk half).
// d(a,b) = ||a||^2 + [||b||^2 - 2 a.b]; bracket minimized, ||a||^2 added in epilogue.
template <int CH_>
__global__ __launch_bounds__(256) void chamfer_main(
    const float* __restrict__ x, const float* __restrict__ y,
    float* __restrict__ pmin, float* __restrict__ out) {
    constexpr int MCHUNK = NPTS / CH_;
    constexpr int MP = MCHUNK / 2;
    __shared__ alignas(16) v2f qs2[MP * 4];

    const int b   = blockIdx.y;
    const int z   = blockIdx.z;          // 0 .. 2*CH-1
    const int dir = z / CH_;
    const int ch  = z % CH_;
    const int tid = threadIdx.x;

    const float* A = (dir == 0) ? x : y;
    const float* B = (dir == 0) ? y : x;

    // out is re-poisoned before every call; zero it (reduce runs strictly after main).
    if (blockIdx.x == 0 && b == 0 && z == 0 && tid == 0) out[0] = 0.0f;

    // Stage chunk into LDS in m-pair layout. float index: 8*mp + 2*comp + (m&1).
    const float* bb = B + (size_t)b * 3 * NPTS + (size_t)ch * MCHUNK;
    float* qf = (float*)qs2;
    for (int m = tid; m < MCHUNK; m += 256) {
        float bxv = bb[m];
        float byv = bb[NPTS + m];
        float bzv = bb[2 * NPTS + m];
        int base = 8 * (m >> 1) + (m & 1);
        qf[base + 0] = -2.0f * bxv;
        qf[base + 2] = -2.0f * byv;
        qf[base + 4] = -2.0f * bzv;
        qf[base + 6] = bxv * bxv + byv * byv + bzv * bzv;
    }

    // Load IPT a-points, scalar regs (coalesced global reads).
    const int i0 = blockIdx.x * (256 * IPT) + tid;
    const float* ab = A + (size_t)b * 3 * NPTS;
    float ax[IPT], ay[IPT], az[IPT], xx[IPT];
    v2f vmin2[IPT];
#pragma unroll
    for (int k = 0; k < IPT; ++k) {
        int i = i0 + k * 256;
        ax[k] = ab[i];
        ay[k] = ab[NPTS + i];
        az[k] = ab[2 * NPTS + i];
        xx[k] = fmaf(ax[k], ax[k], fmaf(ay[k], ay[k], az[k] * az[k]));
        vmin2[k] = v2f{3.4e38f, 3.4e38f};
    }
    __syncthreads();

    // Inner scan: 2 m-pairs (4 m) per iteration: 4 ds_read_b128 +
    // IPT*(6 pk_fma + 2 min3).
    const float4* qv4 = (const float4*)qs2;
    for (int mp = 0; mp < MP; mp += 2) {
        float4 h0 = qv4[2 * mp];         // {cx.lo, cx.hi, cy.lo, cy.hi}   (pair mp)
        float4 h1 = qv4[2 * mp + 1];     // {cz.lo, cz.hi, cw.lo, cw.hi}
        float4 h2 = qv4[2 * mp + 2];     // pair mp+1
        float4 h3 = qv4[2 * mp + 3];
        v2f cx0 = v2f{h0.x, h0.y}, cy0 = v2f{h0.z, h0.w};
        v2f cz0 = v2f{h1.x, h1.y}, cw0 = v2f{h1.z, h1.w};
        v2f cx1 = v2f{h2.x, h2.y}, cy1 = v2f{h2.z, h2.w};
        v2f cz1 = v2f{h3.x, h3.y}, cw1 = v2f{h3.z, h3.w};
#pragma unroll
        for (int k = 0; k < IPT; ++k) {
            v2f sx = splat2(ax[k]);      // loop-invariant, hoisted
            v2f sy = splat2(ay[k]);
            v2f sz = splat2(az[k]);
            v2f t0 = V2FMA(sx, cx0, cw0);
            t0 = V2FMA(sy, cy0, t0);
            t0 = V2FMA(sz, cz0, t0);
            v2f t1 = V2FMA(sx, cx1, cw1);
            t1 = V2FMA(sy, cy1, t1);
            t1 = V2FMA(sz, cz1, t1);
            // min3 per component: vmin = min(vmin, t0, t1)
            vmin2[k].x = fminf(fminf(t0.x, t1.x), vmin2[k].x);
            vmin2[k].y = fminf(fminf(t0.y, t1.y), vmin2[k].y);
        }
    }

    // Epilogue: fold lo/hi, add ||a||^2, write partial mins (coalesced in i).
    float* pout = pmin + ((size_t)(dir * NB + b) * CH_ + ch) * NPTS;
#pragma unroll
    for (int k = 0; k < IPT; ++k) {
        pout[i0 + k * 256] = fminf(vmin2[k].x, vmin2[k].y) + xx[k];
    }
}

// ---------------- reduce: min over CH chunks, sum all, one atomic/block ----------------
template <int CH_>
__global__ __launch_bounds__(256) void chamfer_reduce(
    const float* __restrict__ pmin, float* __restrict__ out) {
    __shared__ float sred[4];
    const int u  = blockIdx.x * 256 + threadIdx.x;     // 0 .. 2*NB*NPTS-1
    const int i  = u & (NPTS - 1);
    const int db = u >> 12;                            // dir*NB+b
    const float* base = pmin + (size_t)db * CH_ * NPTS + i;
    float vm = base[0];
#pragma unroll
    for (int c = 1; c < CH_; ++c) vm = fminf(vm, base[(size_t)c * NPTS]);

    float s = vm;
#pragma unroll
    for (int off = 32; off > 0; off >>= 1) s += __shfl_down(s, off, 64);
    const int lane = threadIdx.x & 63;
    const int wid  = threadIdx.x >> 6;
    if (lane == 0) sred[wid] = s;
    __syncthreads();
    if (threadIdx.x == 0) {
        float tot = sred[0] + sred[1] + sred[2] + sred[3];
        atomicAdd(out, tot * OUT_SCALE);
    }
}

// ---------------- fallback (tiny ws): slow but correct ----------------
__global__ void zero_out(float* out) { out[0] = 0.0f; }

__global__ __launch_bounds__(256) void chamfer_direct(
    const float* __restrict__ x, const float* __restrict__ y,
    float* __restrict__ out) {
    const int b   = blockIdx.y;
    const int dir = blockIdx.z;
    const float* A  = (dir == 0) ? x : y;
    const float* Bm = (dir == 0) ? y : x;
    const int i = blockIdx.x * blockDim.x + threadIdx.x;
    const float* abase = A + (size_t)b * 3 * NPTS + i;
    const float ax = abase[0], ay = abase[NPTS], az = abase[2 * NPTS];
    const float* bbase = Bm + (size_t)b * 3 * NPTS;
    float vmin = 3.4e38f;
#pragma unroll 8
    for (int m = 0; m < NPTS; ++m) {
        float dx = ax - bbase[m];
        float dy = ay - bbase[NPTS + m];
        float dz = az - bbase[2 * NPTS + m];
        float t = dx * dx;
        t = fmaf(dy, dy, t);
        t = fmaf(dz, dz, t);
        vmin = fminf(vmin, t);
    }
    float s = vmin;
#pragma unroll
    for (int off = 32; off > 0; off >>= 1) s += __shfl_down(s, off, 64);
    if ((threadIdx.x & 63) == 0) atomicAdd(out, s * OUT_SCALE);
}

extern "C" void kernel_launch(void* const* d_in, const int* in_sizes, int n_in,
                              void* d_out, int out_size, void* d_ws, size_t ws_size,
                              hipStream_t stream) {
    const float* x = (const float*)d_in[0];
    const float* y = (const float*)d_in[1];
    float* out  = (float*)d_out;
    float* pmin = (float*)d_ws;

    const dim3 blk(256);
    const int gx = NPTS / (256 * IPT);                     // 1

    const size_t need64 = 2ull * NB * 64 * NPTS * sizeof(float);   // 16 MiB
    const size_t need8  = 2ull * NB * 8  * NPTS * sizeof(float);   // 2 MiB

    if (ws_size >= need64) {
        chamfer_main<64><<<dim3(gx, NB, 2 * 64), blk, 0, stream>>>(x, y, pmin, out);
        chamfer_reduce<64><<<dim3((2 * NB * NPTS) / 256), blk, 0, stream>>>(pmin, out);
    } else if (ws_size >= need8) {
        chamfer_main<8><<<dim3(gx, NB, 2 * 8), blk, 0, stream>>>(x, y, pmin, out);
        chamfer_reduce<8><<<dim3((2 * NB * NPTS) / 256), blk, 0, stream>>>(pmin, out);
    } else {
        zero_out<<<dim3(1), dim3(1), 0, stream>>>(out);
        chamfer_direct<<<dim3(NPTS / 256, NB, 2), blk, 0, stream>>>(x, y, out);
    }
}

// Round 9
// 80.701 us; speedup vs baseline: 1.0784x; 1.0784x over previous
//
#include <hip/hip_runtime.h>

#define NB 8
#define NPTS 4096
#define IPT 8                       // a-points per thread (scalar A-side)
#define OUT_SCALE (1.0f / (float)(NPTS * NB))

typedef float v2f __attribute__((ext_vector_type(2)));

#if defined(__has_builtin) && __has_builtin(__builtin_elementwise_fma)
#define V2FMA(a, b, c) __builtin_elementwise_fma((a), (b), (c))
#else
static __device__ inline v2f V2FMA(v2f a, v2f b, v2f c) {
    v2f r; r.x = fmaf(a.x, b.x, c.x); r.y = fmaf(a.y, b.y, c.y); return r;
}
#endif
#if defined(__has_builtin) && __has_builtin(__builtin_elementwise_min)
#define V2MIN(a, b) __builtin_elementwise_min((a), (b))
#else
static __device__ inline v2f V2MIN(v2f a, v2f b) {
    v2f r; r.x = fminf(a.x, b.x); r.y = fminf(a.y, b.y); return r;
}
#endif

static __device__ inline v2f splat2(float s) { v2f r; r.x = s; r.y = s; return r; }

// ---------------- main: grid (NPTS/(256*IPT)=2, NB, 2*CH), block 256 ----------------
// LDS packed over m-PAIRS (32B/pair) -> 2 ds_read_b128 per 2-m per wave.
// R9 changes vs R7:
//   * depth-1 software pipeline: prefetch m-pair i+1's reads, compute m-pair i
//     (lgkm wait lands AFTER the compute -> wave never exposes LDS latency)
//   * per-wave + per-block start-offset skew on the circular m-scan, so resident
//     waves don't convoy (LDS bursts overlap other waves' VALU bursts).
// d(a,b) = ||a||^2 + [||b||^2 - 2 a.b]; bracket minimized, ||a||^2 added in epilogue.
template <int CH_>
__global__ __launch_bounds__(256) void chamfer_main(
    const float* __restrict__ x, const float* __restrict__ y,
    float* __restrict__ pmin, float* __restrict__ out) {
    constexpr int MCHUNK = NPTS / CH_;
    constexpr int MP = MCHUNK / 2;          // m-pairs; power of 2
    __shared__ alignas(16) v2f qs2[MP * 4];

    const int b   = blockIdx.y;
    const int z   = blockIdx.z;          // 0 .. 2*CH-1
    const int dir = z / CH_;
    const int ch  = z % CH_;
    const int tid = threadIdx.x;

    const float* A = (dir == 0) ? x : y;
    const float* B = (dir == 0) ? y : x;

    // out is re-poisoned before every call; zero it (reduce runs strictly after main).
    if (blockIdx.x == 0 && b == 0 && z == 0 && tid == 0) out[0] = 0.0f;

    // Stage chunk into LDS in m-pair layout. float index: 8*mp + 2*comp + (m&1).
    const float* bb = B + (size_t)b * 3 * NPTS + (size_t)ch * MCHUNK;
    float* qf = (float*)qs2;
    for (int m = tid; m < MCHUNK; m += 256) {
        float bxv = bb[m];
        float byv = bb[NPTS + m];
        float bzv = bb[2 * NPTS + m];
        int base = 8 * (m >> 1) + (m & 1);
        qf[base + 0] = -2.0f * bxv;
        qf[base + 2] = -2.0f * byv;
        qf[base + 4] = -2.0f * bzv;
        qf[base + 6] = bxv * bxv + byv * byv + bzv * bzv;
    }

    // Load IPT a-points, scalar regs (coalesced global reads).
    const int i0 = blockIdx.x * (256 * IPT) + tid;
    const float* ab = A + (size_t)b * 3 * NPTS;
    float ax[IPT], ay[IPT], az[IPT], xx[IPT];
    v2f vmin2[IPT];
#pragma unroll
    for (int k = 0; k < IPT; ++k) {
        int i = i0 + k * 256;
        ax[k] = ab[i];
        ay[k] = ab[NPTS + i];
        az[k] = ab[2 * NPTS + i];
        xx[k] = fmaf(ax[k], ax[k], fmaf(ay[k], ay[k], az[k] * az[k]));
        vmin2[k] = v2f{3.4e38f, 3.4e38f};
    }
    __syncthreads();

    // Circular scan with skewed start + depth-1 prefetch.
    const float4* qv4 = (const float4*)qs2;
    const int wid = tid >> 6;
    int idx = (wid * (MP / 4) + (z & 1) * (MP / 8) + blockIdx.x * (MP / 16)) & (MP - 1);
    float4 h0 = qv4[2 * idx];
    float4 h1 = qv4[2 * idx + 1];
#pragma unroll 2
    for (int it = 0; it < MP; ++it) {
        const int nidx = (idx + 1) & (MP - 1);
        float4 n0 = qv4[2 * nidx];       // prefetch next m-pair
        float4 n1 = qv4[2 * nidx + 1];
        v2f cx2 = v2f{h0.x, h0.y}, cy2 = v2f{h0.z, h0.w};
        v2f cz2 = v2f{h1.x, h1.y}, cw2 = v2f{h1.z, h1.w};
#pragma unroll
        for (int k = 0; k < IPT; ++k) {
            v2f t = V2FMA(splat2(ax[k]), cx2, cw2);   // splats hoisted
            t = V2FMA(splat2(ay[k]), cy2, t);
            t = V2FMA(splat2(az[k]), cz2, t);
            vmin2[k] = V2MIN(vmin2[k], t);
        }
        h0 = n0; h1 = n1; idx = nidx;
    }

    // Epilogue: fold lo/hi, add ||a||^2, write partial mins (coalesced in i).
    float* pout = pmin + ((size_t)(dir * NB + b) * CH_ + ch) * NPTS;
#pragma unroll
    for (int k = 0; k < IPT; ++k) {
        pout[i0 + k * 256] = fminf(vmin2[k].x, vmin2[k].y) + xx[k];
    }
}

// ---------------- reduce: min over CH chunks, sum all, one atomic/block ----------------
template <int CH_>
__global__ __launch_bounds__(256) void chamfer_reduce(
    const float* __restrict__ pmin, float* __restrict__ out) {
    __shared__ float sred[4];
    const int u  = blockIdx.x * 256 + threadIdx.x;     // 0 .. 2*NB*NPTS-1
    const int i  = u & (NPTS - 1);
    const int db = u >> 12;                            // dir*NB+b
    const float* base = pmin + (size_t)db * CH_ * NPTS + i;
    float vm = base[0];
#pragma unroll
    for (int c = 1; c < CH_; ++c) vm = fminf(vm, base[(size_t)c * NPTS]);

    float s = vm;
#pragma unroll
    for (int off = 32; off > 0; off >>= 1) s += __shfl_down(s, off, 64);
    const int lane = threadIdx.x & 63;
    const int wid  = threadIdx.x >> 6;
    if (lane == 0) sred[wid] = s;
    __syncthreads();
    if (threadIdx.x == 0) {
        float tot = sred[0] + sred[1] + sred[2] + sred[3];
        atomicAdd(out, tot * OUT_SCALE);
    }
}

// ---------------- fallback (tiny ws): slow but correct ----------------
__global__ void zero_out(float* out) { out[0] = 0.0f; }

__global__ __launch_bounds__(256) void chamfer_direct(
    const float* __restrict__ x, const float* __restrict__ y,
    float* __restrict__ out) {
    const int b   = blockIdx.y;
    const int dir = blockIdx.z;
    const float* A  = (dir == 0) ? x : y;
    const float* Bm = (dir == 0) ? y : x;
    const int i = blockIdx.x * blockDim.x + threadIdx.x;
    const float* abase = A + (size_t)b * 3 * NPTS + i;
    const float ax = abase[0], ay = abase[NPTS], az = abase[2 * NPTS];
    const float* bbase = Bm + (size_t)b * 3 * NPTS;
    float vmin = 3.4e38f;
#pragma unroll 8
    for (int m = 0; m < NPTS; ++m) {
        float dx = ax - bbase[m];
        float dy = ay - bbase[NPTS + m];
        float dz = az - bbase[2 * NPTS + m];
        float t = dx * dx;
        t = fmaf(dy, dy, t);
        t = fmaf(dz, dz, t);
        vmin = fminf(vmin, t);
    }
    float s = vmin;
#pragma unroll
    for (int off = 32; off > 0; off >>= 1) s += __shfl_down(s, off, 64);
    if ((threadIdx.x & 63) == 0) atomicAdd(out, s * OUT_SCALE);
}

extern "C" void kernel_launch(void* const* d_in, const int* in_sizes, int n_in,
                              void* d_out, int out_size, void* d_ws, size_t ws_size,
                              hipStream_t stream) {
    const float* x = (const float*)d_in[0];
    const float* y = (const float*)d_in[1];
    float* out  = (float*)d_out;
    float* pmin = (float*)d_ws;

    const dim3 blk(256);
    const int gx = NPTS / (256 * IPT);                     // 2

    const size_t need32 = 2ull * NB * 32 * NPTS * sizeof(float);   // 16 MiB (floats*4)
    const size_t need8  = 2ull * NB * 8  * NPTS * sizeof(float);

    if (ws_size >= need32) {
        chamfer_main<32><<<dim3(gx, NB, 2 * 32), blk, 0, stream>>>(x, y, pmin, out);
        chamfer_reduce<32><<<dim3((2 * NB * NPTS) / 256), blk, 0, stream>>>(pmin, out);
    } else if (ws_size >= need8) {
        chamfer_main<8><<<dim3(gx, NB, 2 * 8), blk, 0, stream>>>(x, y, pmin, out);
        chamfer_reduce<8><<<dim3((2 * NB * NPTS) / 256), blk, 0, stream>>>(pmin, out);
    } else {
        zero_out<<<dim3(1), dim3(1), 0, stream>>>(out);
        chamfer_direct<<<dim3(NPTS / 256, NB, 2), blk, 0, stream>>>(x, y, out);
    }
}